// Round 1
// baseline (415.147 us; speedup 1.0000x reference)
//
#include <hip/hip_runtime.h>

#define BATCH 32
#define SEQT  2048
#define INSZ  256
#define RSV   512
#define MTOT  (BATCH * SEQT)   // 65536 GEMM rows
#define BM 128
#define BN 128
#define BK 32
#define LSTR 72   // bf16 elems per LDS row: 32 hi | 32 lo | 8 pad (144 B)

typedef __attribute__((ext_vector_type(8))) short bf16x8;
typedef __attribute__((ext_vector_type(4))) float f32x4;

// fp32 -> bf16 round-to-nearest-even (bit pattern)
static __device__ __forceinline__ unsigned short f2bf(float f) {
    unsigned u = __builtin_bit_cast(unsigned, f);
    u += 0x7fffu + ((u >> 16) & 1u);
    return (unsigned short)(u >> 16);
}

// C[m][n] = sum_k X[m][k] * W[n][k], fp32 in/out, bf16 split 3-pass MFMA.
// 128x128 tile, BK=32, 4 waves (2x2 of 64x64), 16x16x32 bf16 MFMA.
__global__ __launch_bounds__(256) void esn_gemm(const float* __restrict__ X,
                                                const float* __restrict__ W,
                                                float* __restrict__ U) {
    __shared__ unsigned short Ash[BM * LSTR];
    __shared__ unsigned short Bsh[BN * LSTR];

    const int tid  = threadIdx.x;
    const int lane = tid & 63;
    const int wid  = tid >> 6;
    const int wr   = wid >> 1, wc = wid & 1;
    const int bm   = blockIdx.x >> 2, bn = blockIdx.x & 3;

    const int srow = tid >> 3;          // 0..31
    const int scol = (tid & 7) * 4;     // 0,4,...,28 (float/bf16 col index)

    f32x4 acc[4][4] = {};

    for (int ks = 0; ks < INSZ / BK; ++ks) {
        __syncthreads();
        // ---- stage: global fp32 -> split bf16 hi/lo -> LDS ----
        #pragma unroll
        for (int p = 0; p < 4; ++p) {
            const int row = srow + p * 32;
            float4 av = *(const float4*)(X + (size_t)(bm * BM + row) * INSZ + ks * BK + scol);
            float4 bv = *(const float4*)(W + (size_t)(bn * BN + row) * INSZ + ks * BK + scol);
            float a4[4] = {av.x, av.y, av.z, av.w};
            float b4[4] = {bv.x, bv.y, bv.z, bv.w};
            unsigned ah[4], al[4], bh[4], bl[4];
            #pragma unroll
            for (int j = 0; j < 4; ++j) {
                unsigned short h = f2bf(a4[j]);
                float hf = __builtin_bit_cast(float, (unsigned)h << 16);
                ah[j] = h; al[j] = f2bf(a4[j] - hf);
                h = f2bf(b4[j]);
                hf = __builtin_bit_cast(float, (unsigned)h << 16);
                bh[j] = h; bl[j] = f2bf(b4[j] - hf);
            }
            uint2 v;
            v.x = ah[0] | (ah[1] << 16); v.y = ah[2] | (ah[3] << 16);
            *(uint2*)&Ash[row * LSTR + scol] = v;
            v.x = al[0] | (al[1] << 16); v.y = al[2] | (al[3] << 16);
            *(uint2*)&Ash[row * LSTR + 32 + scol] = v;
            v.x = bh[0] | (bh[1] << 16); v.y = bh[2] | (bh[3] << 16);
            *(uint2*)&Bsh[row * LSTR + scol] = v;
            v.x = bl[0] | (bl[1] << 16); v.y = bl[2] | (bl[3] << 16);
            *(uint2*)&Bsh[row * LSTR + 32 + scol] = v;
        }
        __syncthreads();

        // ---- fragments + 3-pass MFMA ----
        bf16x8 afh[4], afl[4], bfh[4], bfl[4];
        #pragma unroll
        for (int m = 0; m < 4; ++m) {
            const unsigned short* p = &Ash[(wr * 64 + m * 16 + (lane & 15)) * LSTR + (lane >> 4) * 8];
            afh[m] = *(const bf16x8*)p;
            afl[m] = *(const bf16x8*)(p + 32);
        }
        #pragma unroll
        for (int n = 0; n < 4; ++n) {
            const unsigned short* p = &Bsh[(wc * 64 + n * 16 + (lane & 15)) * LSTR + (lane >> 4) * 8];
            bfh[n] = *(const bf16x8*)p;
            bfl[n] = *(const bf16x8*)(p + 32);
        }
        #pragma unroll
        for (int m = 0; m < 4; ++m)
            #pragma unroll
            for (int n = 0; n < 4; ++n) {
                acc[m][n] = __builtin_amdgcn_mfma_f32_16x16x32_bf16(afh[m], bfh[n], acc[m][n], 0, 0, 0);
                acc[m][n] = __builtin_amdgcn_mfma_f32_16x16x32_bf16(afh[m], bfl[n], acc[m][n], 0, 0, 0);
                acc[m][n] = __builtin_amdgcn_mfma_f32_16x16x32_bf16(afl[m], bfh[n], acc[m][n], 0, 0, 0);
            }
    }

    // ---- epilogue: C/D layout col=lane&15, row=(lane>>4)*4+j ----
    #pragma unroll
    for (int m = 0; m < 4; ++m) {
        const int row = bm * BM + wr * 64 + m * 16 + (lane >> 4) * 4;
        #pragma unroll
        for (int n = 0; n < 4; ++n) {
            const int col = bn * BN + wc * 64 + n * 16 + (lane & 15);
            f32x4 v = acc[m][n];
            #pragma unroll
            for (int j = 0; j < 4; ++j)
                U[(size_t)(row + j) * RSV + col] = v[j];
        }
    }
}

// In-place recurrence over d_out (which holds u after esn_gemm).
// out[b,t,r] = tanh(d[r]*out[b,t-1,r] + u[b,t+1,r]), t=0..T-2; out[b,T-1,r]=0.
// One thread per (b,r) chain; reads lead writes by >=1 step -> in-place safe.
__global__ __launch_bounds__(64) void esn_recur(float* __restrict__ OUT,
                                                const float* __restrict__ D) {
    const int gid = blockIdx.x * 64 + threadIdx.x;   // 0..16383
    const int b = gid >> 9;
    const int r = gid & (RSV - 1);
    float* base = OUT + (size_t)b * SEQT * RSV + r;
    const float dd2 = 2.0f * D[r];
    float s = 0.0f;
    float un = base[(size_t)1 * RSV];                // u[t=1]
    for (int t = 0; t < SEQT - 1; ++t) {
        const float u2 = un + un;
        if (t + 2 < SEQT) un = base[(size_t)(t + 2) * RSV];  // prefetch
        const float z2 = __builtin_fmaf(dd2, s, u2);         // 2*(d*s + u)
        const float e  = __expf(z2);                         // e^(2z); inf/0 saturate ok
        const float rc = __builtin_amdgcn_rcpf(1.0f + e);
        s = __builtin_fmaf(-2.0f, rc, 1.0f);                 // tanh(z) = 1 - 2/(1+e^(2z))
        base[(size_t)t * RSV] = s;
    }
    base[(size_t)(SEQT - 1) * RSV] = 0.0f;
}

extern "C" void kernel_launch(void* const* d_in, const int* in_sizes, int n_in,
                              void* d_out, int out_size, void* d_ws, size_t ws_size,
                              hipStream_t stream) {
    const float* X = (const float*)d_in[0];   // [32,2048,256] fp32
    const float* W = (const float*)d_in[1];   // [512,256] fp32
    const float* D = (const float*)d_in[2];   // [512] fp32
    float* OUT = (float*)d_out;               // [32,2048,512] fp32

    esn_gemm<<<dim3((MTOT / BM) * (RSV / BN)), dim3(256), 0, stream>>>(X, W, OUT);
    esn_recur<<<dim3(BATCH * RSV / 64), dim3(64), 0, stream>>>(OUT, D);
}

// Round 2
// 278.750 us; speedup vs baseline: 1.4893x; 1.4893x over previous
//
#include <hip/hip_runtime.h>

#define BATCH 32
#define SEQT  2048
#define INSZ  256
#define RSV   512
#define MTOT  (BATCH * SEQT)   // 65536 GEMM rows
#define BM 128
#define BN 128
#define BK 32
#define LSA 40   // A row: 32 f16 + 8 pad (80 B stride: b128 frags spread banks, 2-way max)
#define LSB 72   // B row: 32 hi | 32 lo | 8 pad (144 B stride)

using f16x8 = __attribute__((ext_vector_type(8))) _Float16;
using f16x4 = __attribute__((ext_vector_type(4))) _Float16;
using f32x4 = __attribute__((ext_vector_type(4))) float;

// C[m][n] = sum_k X[m][k] * W[n][k], fp32 in/out.
// 2-pass fp16 MFMA: W split into fp16 hi+lo (~22 mantissa bits), X single fp16.
// 128x128 tile, BK=32, 4 waves (2x2 of 64x64), 16x16x32 f16 MFMA.
__global__ __launch_bounds__(256) void esn_gemm(const float* __restrict__ X,
                                                const float* __restrict__ W,
                                                float* __restrict__ U) {
    __shared__ _Float16 Ash[BM * LSA];
    __shared__ _Float16 Bsh[BN * LSB];

    const int tid  = threadIdx.x;
    const int lane = tid & 63;
    const int wid  = tid >> 6;
    const int wr   = wid >> 1, wc = wid & 1;
    const int bm   = blockIdx.x >> 2, bn = blockIdx.x & 3;

    const int srow = tid >> 3;          // 0..31
    const int scol = (tid & 7) * 4;     // 0,4,...,28

    f32x4 acc[4][4] = {};

    for (int ks = 0; ks < INSZ / BK; ++ks) {
        __syncthreads();
        // ---- stage: global fp32 -> fp16 (A) / fp16 hi+lo (B) -> LDS ----
        #pragma unroll
        for (int p = 0; p < 4; ++p) {
            const int row = srow + p * 32;
            float4 av = *(const float4*)(X + (size_t)(bm * BM + row) * INSZ + ks * BK + scol);
            float4 bv = *(const float4*)(W + (size_t)(bn * BN + row) * INSZ + ks * BK + scol);
            float a4[4] = {av.x, av.y, av.z, av.w};
            float b4[4] = {bv.x, bv.y, bv.z, bv.w};
            f16x4 ah, bh, bl;
            #pragma unroll
            for (int j = 0; j < 4; ++j) {
                ah[j] = (_Float16)a4[j];
                _Float16 h = (_Float16)b4[j];
                bh[j] = h;
                bl[j] = (_Float16)(b4[j] - (float)h);
            }
            *(f16x4*)&Ash[row * LSA + scol] = ah;
            *(f16x4*)&Bsh[row * LSB + scol] = bh;
            *(f16x4*)&Bsh[row * LSB + 32 + scol] = bl;
        }
        __syncthreads();

        // ---- fragments + 2-pass MFMA ----
        f16x8 af[4], bfh[4], bfl[4];
        #pragma unroll
        for (int m = 0; m < 4; ++m)
            af[m] = *(const f16x8*)&Ash[(wr * 64 + m * 16 + (lane & 15)) * LSA + (lane >> 4) * 8];
        #pragma unroll
        for (int n = 0; n < 4; ++n) {
            const _Float16* p = &Bsh[(wc * 64 + n * 16 + (lane & 15)) * LSB + (lane >> 4) * 8];
            bfh[n] = *(const f16x8*)p;
            bfl[n] = *(const f16x8*)(p + 32);
        }
        #pragma unroll
        for (int m = 0; m < 4; ++m)
            #pragma unroll
            for (int n = 0; n < 4; ++n) {
                acc[m][n] = __builtin_amdgcn_mfma_f32_16x16x32_f16(af[m], bfh[n], acc[m][n], 0, 0, 0);
                acc[m][n] = __builtin_amdgcn_mfma_f32_16x16x32_f16(af[m], bfl[n], acc[m][n], 0, 0, 0);
            }
    }

    // ---- epilogue: C/D layout col=lane&15, row=(lane>>4)*4+j ----
    #pragma unroll
    for (int m = 0; m < 4; ++m) {
        const int row = bm * BM + wr * 64 + m * 16 + (lane >> 4) * 4;
        #pragma unroll
        for (int n = 0; n < 4; ++n) {
            const int col = bn * BN + wc * 64 + n * 16 + (lane & 15);
            f32x4 v = acc[m][n];
            #pragma unroll
            for (int j = 0; j < 4; ++j)
                U[(size_t)(row + j) * RSV + col] = v[j];
        }
    }
}

// In-place recurrence over d_out (holds u after esn_gemm).
// out[b,t,r] = tanh(d[r]*out_prev + u[b,t+1,r]), t=0..2046; out[b,2047,r]=0.
// One thread per (b,r) chain. Depth-32 register prefetch (4 buffers of 8,
// all statically indexed) to cover ~900cy HBM latency at 1 wave/CU.
#define K2LOG2E 2.8853900817779268f  // 2*log2(e)

#define STEP(uv, tt) do {                                   \
    float z  = __builtin_fmaf(dK, s, (uv) * K2LOG2E);       \
    float p  = __builtin_amdgcn_exp2f(z);                   \
    float rc = __builtin_amdgcn_rcpf(1.0f + p);             \
    s = __builtin_fmaf(-2.0f, rc, 1.0f);                    \
    base[(size_t)(tt) * RSV] = s;                           \
} while (0)

// compute steps t0..t0+7 from buf, refill buf with u[t0+33..t0+40] (clamped)
#define PROC8(buf, t0) do {                                 \
    _Pragma("unroll")                                       \
    for (int j = 0; j < 8; ++j) {                           \
        STEP(buf[j], (t0) + j);                             \
        int idx = (t0) + 33 + j;                            \
        idx = idx < SEQT ? idx : SEQT - 1;                  \
        buf[j] = base[(size_t)idx * RSV];                   \
    }                                                       \
} while (0)

__global__ __launch_bounds__(64) void esn_recur(float* __restrict__ OUT,
                                                const float* __restrict__ D) {
    const int gid = blockIdx.x * 64 + threadIdx.x;   // 0..16383
    const int b = gid >> 9;
    const int r = gid & (RSV - 1);
    float* base = OUT + (size_t)b * SEQT * RSV + r;
    const float dK = D[r] * K2LOG2E;                 // d * 2log2e
    float s = 0.0f;

    float bA[8], bB[8], bC[8], bD[8];
    #pragma unroll
    for (int j = 0; j < 8; ++j) bA[j] = base[(size_t)(1 + j) * RSV];
    #pragma unroll
    for (int j = 0; j < 8; ++j) bB[j] = base[(size_t)(9 + j) * RSV];
    #pragma unroll
    for (int j = 0; j < 8; ++j) bC[j] = base[(size_t)(17 + j) * RSV];
    #pragma unroll
    for (int j = 0; j < 8; ++j) bD[j] = base[(size_t)(25 + j) * RSV];

    int t = 0;
    for (int it = 0; it < 63; ++it) {   // 63*32 = 2016 steps
        PROC8(bA, t);
        PROC8(bB, t + 8);
        PROC8(bC, t + 16);
        PROC8(bD, t + 24);
        t += 32;
    }
    // tail: steps 2016..2046 (31 steps), buffers already hold u[2017..2047]
    #pragma unroll
    for (int j = 0; j < 8; ++j) STEP(bA[j], 2016 + j);
    #pragma unroll
    for (int j = 0; j < 8; ++j) STEP(bB[j], 2024 + j);
    #pragma unroll
    for (int j = 0; j < 8; ++j) STEP(bC[j], 2032 + j);
    #pragma unroll
    for (int j = 0; j < 7; ++j) STEP(bD[j], 2040 + j);

    base[(size_t)(SEQT - 1) * RSV] = 0.0f;
}

extern "C" void kernel_launch(void* const* d_in, const int* in_sizes, int n_in,
                              void* d_out, int out_size, void* d_ws, size_t ws_size,
                              hipStream_t stream) {
    const float* X = (const float*)d_in[0];   // [32,2048,256] fp32
    const float* W = (const float*)d_in[1];   // [512,256] fp32
    const float* D = (const float*)d_in[2];   // [512] fp32
    float* OUT = (float*)d_out;               // [32,2048,512] fp32

    esn_gemm<<<dim3((MTOT / BM) * (RSV / BN)), dim3(256), 0, stream>>>(X, W, OUT);
    esn_recur<<<dim3(BATCH * RSV / 64), dim3(64), 0, stream>>>(OUT, D);
}